// Round 5
// baseline (134.616 us; speedup 1.0000x reference)
//
#include <hip/hip_runtime.h>

typedef float f32x4 __attribute__((ext_vector_type(4)));
typedef short bf16x8 __attribute__((ext_vector_type(8)));

#define MFMA_BF16(a, b, c) __builtin_amdgcn_mfma_f32_16x16x32_bf16((a), (b), (c), 0, 0, 0)

#define GLDS16(gp, lp) __builtin_amdgcn_global_load_lds( \
    (const __attribute__((address_space(1))) unsigned int*)(gp), \
    (__attribute__((address_space(3))) unsigned int*)(lp), 16, 0, 0)

__device__ __forceinline__ ushort f2bf(float f) {
    unsigned int u = __float_as_uint(f);
    return (ushort)((u + 0x7FFFu + ((u >> 16) & 1u)) >> 16);
}

__device__ __forceinline__ float fexp2(float x) {
#if __has_builtin(__builtin_amdgcn_exp2f)
    return __builtin_amdgcn_exp2f(x);
#else
    return exp2f(x);
#endif
}

// ---------------- prep: cvt x + transpose/cvt both weight matrices, one launch ----------------
// blocks [0,2048): cvt x flat; [2048,3776): tcvt w_qkv; [3776,4352): tcvt w_out
__global__ __launch_bounds__(256) void prep_kernel(
    const float* __restrict__ x, const float* __restrict__ wq, const float* __restrict__ wo,
    ushort* __restrict__ xb, ushort* __restrict__ wqbt, ushort* __restrict__ wobt)
{
    __shared__ float tile[32][33];
    const int bid = blockIdx.x;
    if (bid < 2048) {
        const float4* src = (const float4*)x;
        ushort4* dst = (ushort4*)xb;
        for (int i = bid * 256 + threadIdx.x; i < 1572864; i += 2048 * 256) {
            float4 v = src[i];
            ushort4 o;
            o.x = f2bf(v.x); o.y = f2bf(v.y); o.z = f2bf(v.z); o.w = f2bf(v.w);
            dst[i] = o;
        }
        return;
    }
    const float* src; ushort* dst; int K, N, bx, by;
    if (bid < 3776) {
        const int L = bid - 2048;
        src = wq; dst = wqbt; K = 768; N = 2304; bx = L % 72; by = L / 72;
    } else {
        const int L = bid - 3776;
        src = wo; dst = wobt; K = 768; N = 768; bx = L % 24; by = L / 24;
    }
    const int n0 = bx * 32, k0 = by * 32;
    const int c = threadIdx.x & 31, rb = threadIdx.x >> 5;
    #pragma unroll
    for (int i = 0; i < 4; ++i)
        tile[i * 8 + rb][c] = src[(size_t)(k0 + i * 8 + rb) * N + n0 + c];
    __syncthreads();
    #pragma unroll
    for (int i = 0; i < 4; ++i) {
        int nr = i * 8 + rb;
        dst[(size_t)(n0 + nr) * K + k0 + c] = f2bf(tile[c][nr]);
    }
}

// ---------------- GEMM1: qkv = xb @ wqbt^T; BM256 x BN128 x BK64, 8 waves, 3-buf counted-vmcnt ----------------
// grid 576 (xcd-swizzled), block 512. Scatter Q(scaled),K [B,H,S,D], V^T [B,H,D,S].
__global__ __launch_bounds__(512) void gemm_qkv_mfma(
    const ushort* __restrict__ A, const ushort* __restrict__ Bt,
    ushort* __restrict__ Qo, ushort* __restrict__ Ko, ushort* __restrict__ Vo)
{
    __shared__ ushort Al[3][16384];   // 3 x 256x64 bf16 = 96 KiB
    __shared__ ushort Bl[3][8192];    // 3 x 128x64 bf16 = 48 KiB
    const int tid = threadIdx.x, lane = tid & 63;
    const int wv = tid >> 6, lo = lane & 15, hi = lane >> 4;
    const int wr = wv >> 1, wc = wv & 1;        // 4M x 2N wave grid, 64x64 per wave
    const int L = blockIdx.x;
    const int nid = (L & 7) * 72 + (L >> 3);    // bijective: 576 % 8 == 0
    const int n0 = (nid % 18) * 128, m0 = (nid / 18) * 256;

    auto stageA = [&](int bi, int k0) {
        #pragma unroll
        for (int it = 0; it < 4; ++it) {
            const int p = it * 512 + tid;             // 2048 chunks of 16B
            const int row = p >> 3, ch = (p & 7) ^ (row & 7);
            GLDS16(A + (size_t)(m0 + row) * 768 + k0 + ch * 8,
                   &Al[bi][(it * 512 + (tid & 448)) * 8]);
        }
    };
    auto stageB = [&](int bi, int k0) {
        #pragma unroll
        for (int it = 0; it < 2; ++it) {
            const int p = it * 512 + tid;             // 1024 chunks
            const int row = p >> 3, ch = (p & 7) ^ (row & 7);
            GLDS16(Bt + (size_t)(n0 + row) * 768 + k0 + ch * 8,
                   &Bl[bi][(it * 512 + (tid & 448)) * 8]);
        }
    };

    f32x4 acc[4][4];
    #pragma unroll
    for (int i = 0; i < 4; ++i)
        #pragma unroll
        for (int j = 0; j < 4; ++j)
            acc[i][j] = (f32x4){0.f, 0.f, 0.f, 0.f};

    const int region = n0 / 768;                 // 0:Q 1:K 2:V
    const int h = ((n0 % 768) >> 6) + wc;

    // prologue: tiles 0 and 1 in flight (12 loads)
    stageA(0, 0);  stageB(0, 0);
    stageA(1, 64); stageB(1, 64);

    int cur = 0;
    for (int t = 0; t < 12; ++t) {
        // own tile-t loads complete (newest 6 = tile t+1 may stay in flight)
        if (t < 11) asm volatile("s_waitcnt vmcnt(6)" ::: "memory");
        else        asm volatile("s_waitcnt vmcnt(0)" ::: "memory");
        __builtin_amdgcn_s_barrier();            // all waves' tile-t loads landed
        asm volatile("" ::: "memory");
        if (t + 2 < 12) {                        // prefetch 2 tiles ahead
            const int nb = cur ? cur - 1 : 2;    // (t+2)%3
            stageA(nb, (t + 2) * 64);
            stageB(nb, (t + 2) * 64);
        }
        #pragma unroll
        for (int ks = 0; ks < 2; ++ks) {
            bf16x8 af[4], bfr[4];
            #pragma unroll
            for (int i = 0; i < 4; ++i) {
                const int ra = wr * 64 + i * 16 + lo;
                af[i] = *(const bf16x8*)&Al[cur][ra * 64 + (((ks * 4 + hi) ^ (ra & 7)) * 8)];
                const int rb = wc * 64 + i * 16 + lo;
                bfr[i] = *(const bf16x8*)&Bl[cur][rb * 64 + (((ks * 4 + hi) ^ (rb & 7)) * 8)];
            }
            if (region == 2) {
                #pragma unroll
                for (int mi = 0; mi < 4; ++mi)
                    #pragma unroll
                    for (int nj = 0; nj < 4; ++nj)
                        acc[mi][nj] = MFMA_BF16(af[mi], bfr[nj], acc[mi][nj]);
            } else {
                #pragma unroll
                for (int mi = 0; mi < 4; ++mi)
                    #pragma unroll
                    for (int nj = 0; nj < 4; ++nj)
                        acc[mi][nj] = MFMA_BF16(bfr[nj], af[mi], acc[mi][nj]);
            }
        }
        cur = cur == 2 ? 0 : cur + 1;
    }

    if (region == 2) {
        // natural order: reg r -> s-row; ushort4 along s into V^T [d][s]
        #pragma unroll
        for (int mi = 0; mi < 4; ++mi) {
            const int m4 = m0 + wr * 64 + mi * 16 + hi * 4;
            const int b = m4 >> 10, s = m4 & 1023;
            #pragma unroll
            for (int nj = 0; nj < 4; ++nj) {
                const int d = nj * 16 + lo;
                ushort4 pk;
                pk.x = f2bf(acc[mi][nj][0]); pk.y = f2bf(acc[mi][nj][1]);
                pk.z = f2bf(acc[mi][nj][2]); pk.w = f2bf(acc[mi][nj][3]);
                *(ushort4*)&Vo[((size_t)(b * 12 + h) * 64 + d) * 1024 + s] = pk;
            }
        }
    } else {
        // swapped: reg r -> d; ushort4 along d into [s][d]
        ushort* dst = region ? Ko : Qo;
        const float sc = region ? 1.0f : 0.18033688011112042f;  // (1/8)*log2(e) for Q
        #pragma unroll
        for (int mi = 0; mi < 4; ++mi) {
            const int s_idx = m0 + wr * 64 + mi * 16 + lo;
            const int b = s_idx >> 10, s = s_idx & 1023;
            const size_t base = ((size_t)(b * 12 + h) * 1024 + s) * 64;
            #pragma unroll
            for (int nj = 0; nj < 4; ++nj) {
                ushort4 pk;
                pk.x = f2bf(acc[mi][nj][0] * sc); pk.y = f2bf(acc[mi][nj][1] * sc);
                pk.z = f2bf(acc[mi][nj][2] * sc); pk.w = f2bf(acc[mi][nj][3] * sc);
                *(ushort4*)&dst[base + nj * 16 + hi * 4] = pk;
            }
        }
    }
}

// ---------------- Flash attention, bf16 MFMA, no-max softmax, S^T trick ----------------
__global__ __launch_bounds__(256) void attn_mfma_kernel(
    const ushort* __restrict__ Qg, const ushort* __restrict__ Kg,
    const ushort* __restrict__ Vg, ushort* __restrict__ AO)
{
    __shared__ ushort Kl[2][4096];
    __shared__ ushort Vl[2][4096];
    __shared__ ushort Pl[4][32 * 72];

    const int tid = threadIdx.x, lane = tid & 63;
    const int wv = tid >> 6, lo = lane & 15, hi = lane >> 4;
    const int L = blockIdx.x;
    const int xcd = L & 7, g = L >> 3;
    const int qb = g / 12;
    const int bh = xcd * 12 + (g % 12);
    const int b = bh / 12, h = bh % 12;
    const size_t kvbase = (size_t)bh * (1024 * 64);

    bf16x8 qa[2][2];
    const int qrow0 = qb * 128 + wv * 32;
    #pragma unroll
    for (int mi = 0; mi < 2; ++mi)
        #pragma unroll
        for (int ks = 0; ks < 2; ++ks)
            qa[mi][ks] = *(const bf16x8*)&Qg[kvbase + (size_t)(qrow0 + mi * 16 + lo) * 64 + ks * 32 + hi * 8];

    f32x4 o[2][4];
    float lp[2] = {0.f, 0.f};
    #pragma unroll
    for (int mi = 0; mi < 2; ++mi)
        #pragma unroll
        for (int dj = 0; dj < 4; ++dj) o[mi][dj] = (f32x4){0.f, 0.f, 0.f, 0.f};

    auto stage = [&](int bi, int kt) {
        #pragma unroll
        for (int it = 0; it < 2; ++it) {
            const int p = it * 256 + tid;
            const int row = p >> 3, ch = (p & 7) ^ (row & 7);
            GLDS16(Kg + kvbase + (size_t)(kt + row) * 64 + ch * 8, &Kl[bi][(it * 256 + (tid & 192)) * 8]);
        }
        #pragma unroll
        for (int it = 0; it < 2; ++it) {
            const int p = it * 256 + tid;
            const int row = p >> 3, ch = (p & 7) ^ (row & 7);
            GLDS16(Vg + kvbase + (size_t)row * 1024 + kt + ch * 8, &Vl[bi][(it * 256 + (tid & 192)) * 8]);
        }
    };

    stage(0, 0);
    __syncthreads();

    for (int t = 0; t < 16; ++t) {
        const int cur = t & 1;
        if (t < 15) stage(cur ^ 1, (t + 1) * 64);

        f32x4 s[2][4];
        #pragma unroll
        for (int mi = 0; mi < 2; ++mi)
            #pragma unroll
            for (int nj = 0; nj < 4; ++nj) s[mi][nj] = (f32x4){0.f, 0.f, 0.f, 0.f};
        #pragma unroll
        for (int ks = 0; ks < 2; ++ks) {
            bf16x8 kb[4];
            #pragma unroll
            for (int nj = 0; nj < 4; ++nj) {
                const int key = nj * 16 + lo, c = ks * 4 + hi;
                kb[nj] = *(const bf16x8*)&Kl[cur][key * 64 + ((c ^ (key & 7)) * 8)];
            }
            #pragma unroll
            for (int mi = 0; mi < 2; ++mi)
                #pragma unroll
                for (int nj = 0; nj < 4; ++nj)
                    s[mi][nj] = MFMA_BF16(kb[nj], qa[mi][ks], s[mi][nj]);
        }

        #pragma unroll
        for (int mi = 0; mi < 2; ++mi) {
            #pragma unroll
            for (int nj = 0; nj < 4; ++nj) {
                const unsigned int u0 = __float_as_uint(fexp2(s[mi][nj][0]));
                const unsigned int u1 = __float_as_uint(fexp2(s[mi][nj][1]));
                const unsigned int u2 = __float_as_uint(fexp2(s[mi][nj][2]));
                const unsigned int u3 = __float_as_uint(fexp2(s[mi][nj][3]));
                const float t0 = __uint_as_float(u0 & 0xFFFF0000u);
                const float t1 = __uint_as_float(u1 & 0xFFFF0000u);
                const float t2 = __uint_as_float(u2 & 0xFFFF0000u);
                const float t3 = __uint_as_float(u3 & 0xFFFF0000u);
                lp[mi] += (t0 + t1) + (t2 + t3);
                ushort4 pk;
                pk.x = (ushort)(u0 >> 16); pk.y = (ushort)(u1 >> 16);
                pk.z = (ushort)(u2 >> 16); pk.w = (ushort)(u3 >> 16);
                *(ushort4*)&Pl[wv][(mi * 16 + lo) * 72 + nj * 16 + hi * 4] = pk;
            }
        }

        #pragma unroll
        for (int ks = 0; ks < 2; ++ks) {
            bf16x8 pa[2];
            #pragma unroll
            for (int mi = 0; mi < 2; ++mi)
                pa[mi] = *(const bf16x8*)&Pl[wv][(mi * 16 + lo) * 72 + ks * 32 + hi * 8];
            bf16x8 vb[4];
            #pragma unroll
            for (int dj = 0; dj < 4; ++dj) {
                const int d = dj * 16 + lo, c = ks * 4 + hi;
                vb[dj] = *(const bf16x8*)&Vl[cur][d * 64 + ((c ^ (d & 7)) * 8)];
            }
            #pragma unroll
            for (int mi = 0; mi < 2; ++mi)
                #pragma unroll
                for (int dj = 0; dj < 4; ++dj)
                    o[mi][dj] = MFMA_BF16(pa[mi], vb[dj], o[mi][dj]);
        }
        __syncthreads();
    }

    #pragma unroll
    for (int mi = 0; mi < 2; ++mi) {
        float l = lp[mi];
        l += __shfl_xor(l, 16);
        l += __shfl_xor(l, 32);
        #pragma unroll
        for (int r = 0; r < 4; ++r) {
            const float lr = __shfl(l, hi * 4 + r, 16);
            const float rcp = 1.0f / lr;
            const int srow = qrow0 + mi * 16 + hi * 4 + r;
            #pragma unroll
            for (int dj = 0; dj < 4; ++dj)
                AO[((size_t)(b * 1024 + srow)) * 768 + h * 64 + dj * 16 + lo] =
                    f2bf(o[mi][dj][r] * rcp);
        }
    }
}

// ---------------- GEMM2: out = AO @ wobt^T + bias (fp32 out, swapped -> float4 stores) ----------------
__global__ __launch_bounds__(256) void gemm_out_mfma(
    const ushort* __restrict__ A, const ushort* __restrict__ Bt,
    const float* __restrict__ bias, float* __restrict__ C)
{
    __shared__ ushort Al[2][4096];
    __shared__ ushort Bl[2][4096];
    const int tid = threadIdx.x, lane = tid & 63;
    const int wv = tid >> 6, lo = lane & 15, hi = lane >> 4;
    const int wr = wv >> 1, wc = wv & 1;
    const int L = blockIdx.x + 6 * blockIdx.y;
    const int nid = (L & 7) * 48 + (L >> 3);
    const int n0 = (nid % 6) * 128, m0 = (nid / 6) * 128;

    auto stage = [&](int bi, int k0) {
        #pragma unroll
        for (int it = 0; it < 2; ++it) {
            const int p = it * 256 + tid;
            const int row = p >> 2, ch = (p & 3) ^ ((row >> 1) & 3);
            GLDS16(A + (size_t)(m0 + row) * 768 + k0 + ch * 8, &Al[bi][(it * 256 + (tid & 192)) * 8]);
            GLDS16(Bt + (size_t)(n0 + row) * 768 + k0 + ch * 8, &Bl[bi][(it * 256 + (tid & 192)) * 8]);
        }
    };

    f32x4 acc[4][4];
    #pragma unroll
    for (int i = 0; i < 4; ++i)
        #pragma unroll
        for (int j = 0; j < 4; ++j)
            acc[i][j] = (f32x4){0.f, 0.f, 0.f, 0.f};

    stage(0, 0);
    __syncthreads();
    for (int kt = 0; kt < 24; ++kt) {
        const int cur = kt & 1;
        if (kt < 23) stage(cur ^ 1, (kt + 1) * 32);
        bf16x8 af[4], bfr[4];
        #pragma unroll
        for (int i = 0; i < 4; ++i) {
            const int ra = wr * 64 + i * 16 + lo;
            af[i] = *(const bf16x8*)&Al[cur][ra * 32 + ((hi ^ ((ra >> 1) & 3)) * 8)];
            const int rb = wc * 64 + i * 16 + lo;
            bfr[i] = *(const bf16x8*)&Bl[cur][rb * 32 + ((hi ^ ((rb >> 1) & 3)) * 8)];
        }
        #pragma unroll
        for (int mi = 0; mi < 4; ++mi)
            #pragma unroll
            for (int nj = 0; nj < 4; ++nj)
                acc[mi][nj] = MFMA_BF16(bfr[nj], af[mi], acc[mi][nj]);
        __syncthreads();
    }

    const int ncol0 = n0 + wc * 64;
    #pragma unroll
    for (int mi = 0; mi < 4; ++mi) {
        const int m = m0 + wr * 64 + mi * 16 + lo;
        #pragma unroll
        for (int nj = 0; nj < 4; ++nj) {
            const int nb = ncol0 + nj * 16 + hi * 4;
            const float4 bv = *reinterpret_cast<const float4*>(&bias[nb]);
            float4 ov;
            ov.x = acc[mi][nj][0] + bv.x; ov.y = acc[mi][nj][1] + bv.y;
            ov.z = acc[mi][nj][2] + bv.z; ov.w = acc[mi][nj][3] + bv.w;
            *reinterpret_cast<float4*>(&C[(size_t)m * 768 + nb]) = ov;
        }
    }
}

extern "C" void kernel_launch(void* const* d_in, const int* in_sizes, int n_in,
                              void* d_out, int out_size, void* d_ws, size_t ws_size,
                              hipStream_t stream) {
    const float* x     = (const float*)d_in[0];
    const float* w_qkv = (const float*)d_in[1];
    const float* w_out = (const float*)d_in[2];
    const float* b_out = (const float*)d_in[3];
    float* out = (float*)d_out;

    (void)in_sizes; (void)n_in; (void)out_size; (void)ws_size;

    ushort* xb   = (ushort*)d_ws;            // 6291456
    ushort* wqbt = xb + 6291456;             // 1769472  (w_qkv^T bf16 [2304][768])
    ushort* wobt = wqbt + 1769472;           // 589824   (w_out^T bf16 [768][768])
    ushort* Qs   = wobt + 589824;            // 6291456  (Q*0.125*log2e, [B,H,S,D])
    ushort* Ks   = Qs + 6291456;             // 6291456  ([B,H,S,D])
    ushort* Vt   = Ks + 6291456;             // 6291456  ([B,H,D,S])
    ushort* AO   = Vt + 6291456;             // 6291456  ([B,S,E] bf16)

    prep_kernel<<<4352, 256, 0, stream>>>(x, w_qkv, w_out, xb, wqbt, wobt);
    gemm_qkv_mfma<<<576, 512, 0, stream>>>(xb, wqbt, Qs, Ks, Vt);
    attn_mfma_kernel<<<768, 256, 0, stream>>>(Qs, Ks, Vt, AO);
    gemm_out_mfma<<<dim3(6, 64), 256, 0, stream>>>(AO, wobt, b_out, out);
}

// Round 6
// 122.590 us; speedup vs baseline: 1.0981x; 1.0981x over previous
//
#include <hip/hip_runtime.h>

typedef float f32x4 __attribute__((ext_vector_type(4)));
typedef short bf16x8 __attribute__((ext_vector_type(8)));

#define MFMA_BF16(a, b, c) __builtin_amdgcn_mfma_f32_16x16x32_bf16((a), (b), (c), 0, 0, 0)

#define GLDS16(gp, lp) __builtin_amdgcn_global_load_lds( \
    (const __attribute__((address_space(1))) unsigned int*)(gp), \
    (__attribute__((address_space(3))) unsigned int*)(lp), 16, 0, 0)

__device__ __forceinline__ ushort f2bf(float f) {
    unsigned int u = __float_as_uint(f);
    return (ushort)((u + 0x7FFFu + ((u >> 16) & 1u)) >> 16);
}

__device__ __forceinline__ float fexp2(float x) {
#if __has_builtin(__builtin_amdgcn_exp2f)
    return __builtin_amdgcn_exp2f(x);
#else
    return exp2f(x);
#endif
}

// ---------------- prep: cvt x + transpose/cvt both weight matrices, one launch ----------------
__global__ __launch_bounds__(256) void prep_kernel(
    const float* __restrict__ x, const float* __restrict__ wq, const float* __restrict__ wo,
    ushort* __restrict__ xb, ushort* __restrict__ wqbt, ushort* __restrict__ wobt)
{
    __shared__ float tile[32][33];
    const int bid = blockIdx.x;
    if (bid < 2048) {
        const float4* src = (const float4*)x;
        ushort4* dst = (ushort4*)xb;
        for (int i = bid * 256 + threadIdx.x; i < 1572864; i += 2048 * 256) {
            float4 v = src[i];
            ushort4 o;
            o.x = f2bf(v.x); o.y = f2bf(v.y); o.z = f2bf(v.z); o.w = f2bf(v.w);
            dst[i] = o;
        }
        return;
    }
    const float* src; ushort* dst; int K, N, bx, by;
    if (bid < 3776) {
        const int L = bid - 2048;
        src = wq; dst = wqbt; K = 768; N = 2304; bx = L % 72; by = L / 72;
    } else {
        const int L = bid - 3776;
        src = wo; dst = wobt; K = 768; N = 768; bx = L % 24; by = L / 24;
    }
    const int n0 = bx * 32, k0 = by * 32;
    const int c = threadIdx.x & 31, rb = threadIdx.x >> 5;
    #pragma unroll
    for (int i = 0; i < 4; ++i)
        tile[i * 8 + rb][c] = src[(size_t)(k0 + i * 8 + rb) * N + n0 + c];
    __syncthreads();
    #pragma unroll
    for (int i = 0; i < 4; ++i) {
        int nr = i * 8 + rb;
        dst[(size_t)(n0 + nr) * K + k0 + c] = f2bf(tile[c][nr]);
    }
}

// ---------------- GEMM1: 128x128xBK64, 4 waves, 2-buf, counted vmcnt (no drain) ----------------
// grid 1152 (xcd-swizzled), block 256. Scatter Q(scaled),K [B,H,S,D], V^T [B,H,D,S].
__global__ __launch_bounds__(256) void gemm_qkv_mfma(
    const ushort* __restrict__ A, const ushort* __restrict__ Bt,
    ushort* __restrict__ Qo, ushort* __restrict__ Ko, ushort* __restrict__ Vo)
{
    __shared__ ushort Al[2][8192];   // 2 x 128x64 bf16 = 32 KiB
    __shared__ ushort Bl[2][8192];   // 32 KiB
    const int tid = threadIdx.x, lane = tid & 63;
    const int wv = tid >> 6, lo = lane & 15, hi = lane >> 4;
    const int wr = wv >> 1, wc = wv & 1;
    const int L = blockIdx.x;
    const int nid = (L & 7) * 144 + (L >> 3);   // bijective: 1152 % 8 == 0
    const int n0 = (nid % 18) * 128, m0 = (nid / 18) * 128;

    auto stage = [&](int bi, int k0) {
        #pragma unroll
        for (int it = 0; it < 4; ++it) {
            const int p = it * 256 + tid;             // 1024 chunks of 16B
            const int row = p >> 3, ch = (p & 7) ^ (row & 7);
            GLDS16(A + (size_t)(m0 + row) * 768 + k0 + ch * 8,
                   &Al[bi][(it * 256 + (tid & 192)) * 8]);
        }
        #pragma unroll
        for (int it = 0; it < 4; ++it) {
            const int p = it * 256 + tid;
            const int row = p >> 3, ch = (p & 7) ^ (row & 7);
            GLDS16(Bt + (size_t)(n0 + row) * 768 + k0 + ch * 8,
                   &Bl[bi][(it * 256 + (tid & 192)) * 8]);
        }
    };

    f32x4 acc[4][4];
    #pragma unroll
    for (int i = 0; i < 4; ++i)
        #pragma unroll
        for (int j = 0; j < 4; ++j)
            acc[i][j] = (f32x4){0.f, 0.f, 0.f, 0.f};

    const int region = n0 / 768;                 // 0:Q 1:K 2:V
    const int h = ((n0 % 768) >> 6) + wc;

    stage(0, 0);
    stage(1, 64);

    int cur = 0;
    for (int t = 0; t < 12; ++t) {
        // tile t's loads (oldest 8) complete; tile t+1's stay in flight across barrier
        if (t < 11) asm volatile("s_waitcnt vmcnt(8)" ::: "memory");
        else        asm volatile("s_waitcnt vmcnt(0)" ::: "memory");
        __builtin_amdgcn_s_barrier();
        asm volatile("" ::: "memory");

        #pragma unroll
        for (int ks = 0; ks < 2; ++ks) {
            bf16x8 af[4], bfr[4];
            #pragma unroll
            for (int i = 0; i < 4; ++i) {
                const int ra = wr * 64 + i * 16 + lo;
                af[i] = *(const bf16x8*)&Al[cur][ra * 64 + (((ks * 4 + hi) ^ (ra & 7)) * 8)];
                const int rb = wc * 64 + i * 16 + lo;
                bfr[i] = *(const bf16x8*)&Bl[cur][rb * 64 + (((ks * 4 + hi) ^ (rb & 7)) * 8)];
            }
            if (region == 2) {
                #pragma unroll
                for (int mi = 0; mi < 4; ++mi)
                    #pragma unroll
                    for (int nj = 0; nj < 4; ++nj)
                        acc[mi][nj] = MFMA_BF16(af[mi], bfr[nj], acc[mi][nj]);
            } else {
                #pragma unroll
                for (int mi = 0; mi < 4; ++mi)
                    #pragma unroll
                    for (int nj = 0; nj < 4; ++nj)
                        acc[mi][nj] = MFMA_BF16(bfr[nj], af[mi], acc[mi][nj]);
            }
        }

        asm volatile("s_waitcnt lgkmcnt(0)" ::: "memory");
        __builtin_amdgcn_s_barrier();            // all waves done reading buf[cur]
        asm volatile("" ::: "memory");
        if (t + 2 < 12) stage(cur, (t + 2) * 64);  // overwrite freed buffer
        cur ^= 1;
    }

    if (region == 2) {
        #pragma unroll
        for (int mi = 0; mi < 4; ++mi) {
            const int m4 = m0 + wr * 64 + mi * 16 + hi * 4;
            const int b = m4 >> 10, s = m4 & 1023;
            #pragma unroll
            for (int nj = 0; nj < 4; ++nj) {
                const int d = nj * 16 + lo;
                ushort4 pk;
                pk.x = f2bf(acc[mi][nj][0]); pk.y = f2bf(acc[mi][nj][1]);
                pk.z = f2bf(acc[mi][nj][2]); pk.w = f2bf(acc[mi][nj][3]);
                *(ushort4*)&Vo[((size_t)(b * 12 + h) * 64 + d) * 1024 + s] = pk;
            }
        }
    } else {
        ushort* dst = region ? Ko : Qo;
        const float sc = region ? 1.0f : 0.18033688011112042f;  // (1/8)*log2(e) for Q
        #pragma unroll
        for (int mi = 0; mi < 4; ++mi) {
            const int s_idx = m0 + wr * 64 + mi * 16 + lo;
            const int b = s_idx >> 10, s = s_idx & 1023;
            const size_t base = ((size_t)(b * 12 + h) * 1024 + s) * 64;
            #pragma unroll
            for (int nj = 0; nj < 4; ++nj) {
                ushort4 pk;
                pk.x = f2bf(acc[mi][nj][0] * sc); pk.y = f2bf(acc[mi][nj][1] * sc);
                pk.z = f2bf(acc[mi][nj][2] * sc); pk.w = f2bf(acc[mi][nj][3] * sc);
                *(ushort4*)&dst[base + nj * 16 + hi * 4] = pk;
            }
        }
    }
}

// ---------------- Flash attention, bf16 MFMA, no-max softmax, S^T trick ----------------
__global__ __launch_bounds__(256) void attn_mfma_kernel(
    const ushort* __restrict__ Qg, const ushort* __restrict__ Kg,
    const ushort* __restrict__ Vg, ushort* __restrict__ AO)
{
    __shared__ ushort Kl[2][4096];
    __shared__ ushort Vl[2][4096];
    __shared__ ushort Pl[4][32 * 72];

    const int tid = threadIdx.x, lane = tid & 63;
    const int wv = tid >> 6, lo = lane & 15, hi = lane >> 4;
    const int L = blockIdx.x;
    const int xcd = L & 7, g = L >> 3;
    const int qb = g / 12;
    const int bh = xcd * 12 + (g % 12);
    const int b = bh / 12, h = bh % 12;
    const size_t kvbase = (size_t)bh * (1024 * 64);

    bf16x8 qa[2][2];
    const int qrow0 = qb * 128 + wv * 32;
    #pragma unroll
    for (int mi = 0; mi < 2; ++mi)
        #pragma unroll
        for (int ks = 0; ks < 2; ++ks)
            qa[mi][ks] = *(const bf16x8*)&Qg[kvbase + (size_t)(qrow0 + mi * 16 + lo) * 64 + ks * 32 + hi * 8];

    f32x4 o[2][4];
    float lp[2] = {0.f, 0.f};
    #pragma unroll
    for (int mi = 0; mi < 2; ++mi)
        #pragma unroll
        for (int dj = 0; dj < 4; ++dj) o[mi][dj] = (f32x4){0.f, 0.f, 0.f, 0.f};

    auto stage = [&](int bi, int kt) {
        #pragma unroll
        for (int it = 0; it < 2; ++it) {
            const int p = it * 256 + tid;
            const int row = p >> 3, ch = (p & 7) ^ (row & 7);
            GLDS16(Kg + kvbase + (size_t)(kt + row) * 64 + ch * 8, &Kl[bi][(it * 256 + (tid & 192)) * 8]);
        }
        #pragma unroll
        for (int it = 0; it < 2; ++it) {
            const int p = it * 256 + tid;
            const int row = p >> 3, ch = (p & 7) ^ (row & 7);
            GLDS16(Vg + kvbase + (size_t)row * 1024 + kt + ch * 8, &Vl[bi][(it * 256 + (tid & 192)) * 8]);
        }
    };

    stage(0, 0);
    __syncthreads();

    for (int t = 0; t < 16; ++t) {
        const int cur = t & 1;
        if (t < 15) stage(cur ^ 1, (t + 1) * 64);

        f32x4 s[2][4];
        #pragma unroll
        for (int mi = 0; mi < 2; ++mi)
            #pragma unroll
            for (int nj = 0; nj < 4; ++nj) s[mi][nj] = (f32x4){0.f, 0.f, 0.f, 0.f};
        #pragma unroll
        for (int ks = 0; ks < 2; ++ks) {
            bf16x8 kb[4];
            #pragma unroll
            for (int nj = 0; nj < 4; ++nj) {
                const int key = nj * 16 + lo, c = ks * 4 + hi;
                kb[nj] = *(const bf16x8*)&Kl[cur][key * 64 + ((c ^ (key & 7)) * 8)];
            }
            #pragma unroll
            for (int mi = 0; mi < 2; ++mi)
                #pragma unroll
                for (int nj = 0; nj < 4; ++nj)
                    s[mi][nj] = MFMA_BF16(kb[nj], qa[mi][ks], s[mi][nj]);
        }

        #pragma unroll
        for (int mi = 0; mi < 2; ++mi) {
            #pragma unroll
            for (int nj = 0; nj < 4; ++nj) {
                const unsigned int u0 = __float_as_uint(fexp2(s[mi][nj][0]));
                const unsigned int u1 = __float_as_uint(fexp2(s[mi][nj][1]));
                const unsigned int u2 = __float_as_uint(fexp2(s[mi][nj][2]));
                const unsigned int u3 = __float_as_uint(fexp2(s[mi][nj][3]));
                const float t0 = __uint_as_float(u0 & 0xFFFF0000u);
                const float t1 = __uint_as_float(u1 & 0xFFFF0000u);
                const float t2 = __uint_as_float(u2 & 0xFFFF0000u);
                const float t3 = __uint_as_float(u3 & 0xFFFF0000u);
                lp[mi] += (t0 + t1) + (t2 + t3);
                ushort4 pk;
                pk.x = (ushort)(u0 >> 16); pk.y = (ushort)(u1 >> 16);
                pk.z = (ushort)(u2 >> 16); pk.w = (ushort)(u3 >> 16);
                *(ushort4*)&Pl[wv][(mi * 16 + lo) * 72 + nj * 16 + hi * 4] = pk;
            }
        }

        #pragma unroll
        for (int ks = 0; ks < 2; ++ks) {
            bf16x8 pa[2];
            #pragma unroll
            for (int mi = 0; mi < 2; ++mi)
                pa[mi] = *(const bf16x8*)&Pl[wv][(mi * 16 + lo) * 72 + ks * 32 + hi * 8];
            bf16x8 vb[4];
            #pragma unroll
            for (int dj = 0; dj < 4; ++dj) {
                const int d = dj * 16 + lo, c = ks * 4 + hi;
                vb[dj] = *(const bf16x8*)&Vl[cur][d * 64 + ((c ^ (d & 7)) * 8)];
            }
            #pragma unroll
            for (int mi = 0; mi < 2; ++mi)
                #pragma unroll
                for (int dj = 0; dj < 4; ++dj)
                    o[mi][dj] = MFMA_BF16(pa[mi], vb[dj], o[mi][dj]);
        }
        __syncthreads();
    }

    #pragma unroll
    for (int mi = 0; mi < 2; ++mi) {
        float l = lp[mi];
        l += __shfl_xor(l, 16);
        l += __shfl_xor(l, 32);
        #pragma unroll
        for (int r = 0; r < 4; ++r) {
            const float lr = __shfl(l, hi * 4 + r, 16);
            const float rcp = 1.0f / lr;
            const int srow = qrow0 + mi * 16 + hi * 4 + r;
            #pragma unroll
            for (int dj = 0; dj < 4; ++dj)
                AO[((size_t)(b * 1024 + srow)) * 768 + h * 64 + dj * 16 + lo] =
                    f2bf(o[mi][dj][r] * rcp);
        }
    }
}

// ---------------- GEMM2: 128x128xBK64, 2-buf counted vmcnt; fp32 out + bias ----------------
// grid 384 (xcd-swizzled), block 256.
__global__ __launch_bounds__(256) void gemm_out_mfma(
    const ushort* __restrict__ A, const ushort* __restrict__ Bt,
    const float* __restrict__ bias, float* __restrict__ C)
{
    __shared__ ushort Al[2][8192];
    __shared__ ushort Bl[2][8192];
    const int tid = threadIdx.x, lane = tid & 63;
    const int wv = tid >> 6, lo = lane & 15, hi = lane >> 4;
    const int wr = wv >> 1, wc = wv & 1;
    const int L = blockIdx.x;
    const int nid = (L & 7) * 48 + (L >> 3);    // bijective: 384 % 8 == 0
    const int n0 = (nid % 6) * 128, m0 = (nid / 6) * 128;

    auto stage = [&](int bi, int k0) {
        #pragma unroll
        for (int it = 0; it < 4; ++it) {
            const int p = it * 256 + tid;
            const int row = p >> 3, ch = (p & 7) ^ (row & 7);
            GLDS16(A + (size_t)(m0 + row) * 768 + k0 + ch * 8,
                   &Al[bi][(it * 256 + (tid & 192)) * 8]);
        }
        #pragma unroll
        for (int it = 0; it < 4; ++it) {
            const int p = it * 256 + tid;
            const int row = p >> 3, ch = (p & 7) ^ (row & 7);
            GLDS16(Bt + (size_t)(n0 + row) * 768 + k0 + ch * 8,
                   &Bl[bi][(it * 256 + (tid & 192)) * 8]);
        }
    };

    f32x4 acc[4][4];
    #pragma unroll
    for (int i = 0; i < 4; ++i)
        #pragma unroll
        for (int j = 0; j < 4; ++j)
            acc[i][j] = (f32x4){0.f, 0.f, 0.f, 0.f};

    stage(0, 0);
    stage(1, 64);

    int cur = 0;
    for (int t = 0; t < 12; ++t) {
        if (t < 11) asm volatile("s_waitcnt vmcnt(8)" ::: "memory");
        else        asm volatile("s_waitcnt vmcnt(0)" ::: "memory");
        __builtin_amdgcn_s_barrier();
        asm volatile("" ::: "memory");

        #pragma unroll
        for (int ks = 0; ks < 2; ++ks) {
            bf16x8 af[4], bfr[4];
            #pragma unroll
            for (int i = 0; i < 4; ++i) {
                const int ra = wr * 64 + i * 16 + lo;
                af[i] = *(const bf16x8*)&Al[cur][ra * 64 + (((ks * 4 + hi) ^ (ra & 7)) * 8)];
                const int rb = wc * 64 + i * 16 + lo;
                bfr[i] = *(const bf16x8*)&Bl[cur][rb * 64 + (((ks * 4 + hi) ^ (rb & 7)) * 8)];
            }
            #pragma unroll
            for (int mi = 0; mi < 4; ++mi)
                #pragma unroll
                for (int nj = 0; nj < 4; ++nj)
                    acc[mi][nj] = MFMA_BF16(bfr[nj], af[mi], acc[mi][nj]);
        }

        asm volatile("s_waitcnt lgkmcnt(0)" ::: "memory");
        __builtin_amdgcn_s_barrier();
        asm volatile("" ::: "memory");
        if (t + 2 < 12) stage(cur, (t + 2) * 64);
        cur ^= 1;
    }

    const int ncol0 = n0 + wc * 64;
    #pragma unroll
    for (int mi = 0; mi < 4; ++mi) {
        const int m = m0 + wr * 64 + mi * 16 + lo;
        #pragma unroll
        for (int nj = 0; nj < 4; ++nj) {
            const int nb = ncol0 + nj * 16 + hi * 4;
            const float4 bv = *reinterpret_cast<const float4*>(&bias[nb]);
            float4 ov;
            ov.x = acc[mi][nj][0] + bv.x; ov.y = acc[mi][nj][1] + bv.y;
            ov.z = acc[mi][nj][2] + bv.z; ov.w = acc[mi][nj][3] + bv.w;
            *reinterpret_cast<float4*>(&C[(size_t)m * 768 + nb]) = ov;
        }
    }
}

extern "C" void kernel_launch(void* const* d_in, const int* in_sizes, int n_in,
                              void* d_out, int out_size, void* d_ws, size_t ws_size,
                              hipStream_t stream) {
    const float* x     = (const float*)d_in[0];
    const float* w_qkv = (const float*)d_in[1];
    const float* w_out = (const float*)d_in[2];
    const float* b_out = (const float*)d_in[3];
    float* out = (float*)d_out;

    (void)in_sizes; (void)n_in; (void)out_size; (void)ws_size;

    ushort* xb   = (ushort*)d_ws;            // 6291456
    ushort* wqbt = xb + 6291456;             // 1769472  (w_qkv^T bf16 [2304][768])
    ushort* wobt = wqbt + 1769472;           // 589824   (w_out^T bf16 [768][768])
    ushort* Qs   = wobt + 589824;            // 6291456  (Q*0.125*log2e, [B,H,S,D])
    ushort* Ks   = Qs + 6291456;             // 6291456  ([B,H,S,D])
    ushort* Vt   = Ks + 6291456;             // 6291456  ([B,H,D,S])
    ushort* AO   = Vt + 6291456;             // 6291456  ([B,S,E] bf16)

    prep_kernel<<<4352, 256, 0, stream>>>(x, w_qkv, w_out, xb, wqbt, wobt);
    gemm_qkv_mfma<<<1152, 256, 0, stream>>>(xb, wqbt, Qs, Ks, Vt);
    attn_mfma_kernel<<<768, 256, 0, stream>>>(Qs, Ks, Vt, AO);
    gemm_out_mfma<<<384, 256, 0, stream>>>(AO, wobt, b_out, out);
}